// Round 1
// baseline (70.498 us; speedup 1.0000x reference)
//
#include <hip/hip_runtime.h>

// Problem constants (match reference)
constexpr int Bn = 4, Dn = 128, Hn = 128, Wn = 128, Cn = 16;
constexpr int NPIX = Hn * Wn;  // 16384

// ---------------------------------------------------------------------------
// K1: per-batch class counts + mask sum.
// grid = Bn*16 blocks, 256 threads. Predicated register histogram (no runtime
// register indexing -> no scratch), wave shfl reduce, cross-wave LDS, atomics.
// ---------------------------------------------------------------------------
__global__ void k_counts(const int* __restrict__ label,
                         const int* __restrict__ mask,
                         float* __restrict__ counts,    // [Bn][Cn]
                         float* __restrict__ maskSum) { // [Bn]
    int b = blockIdx.x >> 4;        // 16 blocks per batch
    int chunk = blockIdx.x & 15;    // each handles 1024 pixels
    int base = chunk * 1024;
    int tid = threadIdx.x;

    int cnt[Cn];
#pragma unroll
    for (int c = 0; c < Cn; ++c) cnt[c] = 0;
    int msum = 0;

    for (int i = tid; i < 1024; i += 256) {
        int p = base + i;
        int l = label[b * NPIX + p] - 1;
        msum += mask[b * NPIX + p];
#pragma unroll
        for (int c = 0; c < Cn; ++c) cnt[c] += (l == c);
    }

#pragma unroll
    for (int c = 0; c < Cn; ++c)
        for (int off = 32; off; off >>= 1) cnt[c] += __shfl_down(cnt[c], off);
    for (int off = 32; off; off >>= 1) msum += __shfl_down(msum, off);

    __shared__ int red[4][Cn + 1];
    int wid = tid >> 6, lane = tid & 63;
    if (lane == 0) {
#pragma unroll
        for (int c = 0; c < Cn; ++c) red[wid][c] = cnt[c];
        red[wid][Cn] = msum;
    }
    __syncthreads();
    if (tid < Cn + 1) {
        int s = red[0][tid] + red[1][tid] + red[2][tid] + red[3][tid];
        if (tid < Cn) atomicAdd(&counts[b * Cn + tid], (float)s);
        else          atomicAdd(&maskSum[b], (float)s);
    }
}

// ---------------------------------------------------------------------------
// K2: prototype sums. One block per (b, d): protoSum[b][c][d] = sum of
// x[b,d,p] over pixels with label c. Predicated per-class accumulation.
// grid = Bn*Dn = 512 blocks, 256 threads. No atomics (one block per output).
// ---------------------------------------------------------------------------
__global__ void k_proto(const float* __restrict__ x,
                        const int* __restrict__ label,
                        float* __restrict__ protoSum) { // [Bn][Cn][Dn]
    int b = blockIdx.x >> 7;   // Dn=128 blocks per batch
    int d = blockIdx.x & 127;
    int tid = threadIdx.x;

    const float* xp = x + (size_t)(b * Dn + d) * NPIX;
    const int* lp = label + b * NPIX;

    float acc[Cn];
#pragma unroll
    for (int c = 0; c < Cn; ++c) acc[c] = 0.f;

    for (int p = tid; p < NPIX; p += 256) {
        float xv = xp[p];
        int l = lp[p] - 1;
#pragma unroll
        for (int c = 0; c < Cn; ++c) acc[c] += (l == c) ? xv : 0.f;
    }

#pragma unroll
    for (int c = 0; c < Cn; ++c)
        for (int off = 32; off; off >>= 1) acc[c] += __shfl_down(acc[c], off);

    __shared__ float red[4][Cn];
    int wid = tid >> 6, lane = tid & 63;
    if (lane == 0) {
#pragma unroll
        for (int c = 0; c < Cn; ++c) red[wid][c] = acc[c];
    }
    __syncthreads();
    if (tid < Cn) {
        float s = red[0][tid] + red[1][tid] + red[2][tid] + red[3][tid];
        protoSum[((size_t)b * Cn + tid) * Dn + d] = s;
    }
}

// ---------------------------------------------------------------------------
// K3: main metric + CE pass. One thread per pixel. Protos staged in LDS as
// [d][c] so the inner loop reads 4x broadcast ds_read_b128 per d.
// grid = Bn*64 = 256 blocks, 256 threads (64 blocks per batch).
// ---------------------------------------------------------------------------
__global__ void k_main(const float* __restrict__ x,
                       const int* __restrict__ label,
                       const int* __restrict__ mask,
                       const float* __restrict__ protoSum,
                       const float* __restrict__ counts,
                       float* __restrict__ ceSum) { // [Bn]
    int b = blockIdx.x >> 6;
    int p = ((blockIdx.x & 63) << 8) + threadIdx.x;
    int tid = threadIdx.x;

    __shared__ float proto[Dn][Cn];  // 8 KB, [d][c] layout
    for (int i = tid; i < Cn * Dn; i += 256) {
        int c = i >> 7;          // protoSum layout [c][d] -> coalesced read
        int d = i & 127;
        proto[d][c] = protoSum[((size_t)b * Cn + c) * Dn + d] / counts[b * Cn + c];
    }
    __syncthreads();

    float acc[Cn];
#pragma unroll
    for (int c = 0; c < Cn; ++c) acc[c] = 0.f;

    const float* xp = x + (size_t)b * Dn * NPIX + p;
#pragma unroll 4
    for (int d = 0; d < Dn; ++d) {
        float xv = xp[(size_t)d * NPIX];
        float4 q0 = *(const float4*)&proto[d][0];
        float4 q1 = *(const float4*)&proto[d][4];
        float4 q2 = *(const float4*)&proto[d][8];
        float4 q3 = *(const float4*)&proto[d][12];
        acc[0]  += fabsf(xv - q0.x);  acc[1]  += fabsf(xv - q0.y);
        acc[2]  += fabsf(xv - q0.z);  acc[3]  += fabsf(xv - q0.w);
        acc[4]  += fabsf(xv - q1.x);  acc[5]  += fabsf(xv - q1.y);
        acc[6]  += fabsf(xv - q1.z);  acc[7]  += fabsf(xv - q1.w);
        acc[8]  += fabsf(xv - q2.x);  acc[9]  += fabsf(xv - q2.y);
        acc[10] += fabsf(xv - q2.z);  acc[11] += fabsf(xv - q2.w);
        acc[12] += fabsf(xv - q3.x);  acc[13] += fabsf(xv - q3.y);
        acc[14] += fabsf(xv - q3.z);  acc[15] += fabsf(xv - q3.w);
    }

    // epilogue: pd0 = exp(-acc); pd = pd0 - min; CE from log-softmax over c
    float pd0[Cn];
    float mn = 3.4e38f;
#pragma unroll
    for (int c = 0; c < Cn; ++c) {
        pd0[c] = __expf(-acc[c]);
        mn = fminf(mn, pd0[c]);
    }
    float se = 0.f;
#pragma unroll
    for (int c = 0; c < Cn; ++c) se += __expf(pd0[c] - mn);

    int l = label[b * NPIX + p] - 1;
    float pdl = 0.f;
#pragma unroll
    for (int c = 0; c < Cn; ++c) pdl = (l == c) ? (pd0[c] - mn) : pdl;

    float ce = __logf(se) - pdl;
    float m = (float)mask[b * NPIX + p];
    float v = ce * m;

    // block reduce v, one atomic per block
    for (int off = 32; off; off >>= 1) v += __shfl_down(v, off);
    __shared__ float r2[4];
    int wid = tid >> 6, lane = tid & 63;
    if (lane == 0) r2[wid] = v;
    __syncthreads();
    if (tid == 0) atomicAdd(&ceSum[b], r2[0] + r2[1] + r2[2] + r2[3]);
}

// ---------------------------------------------------------------------------
// K4: final scalar combine
// ---------------------------------------------------------------------------
__global__ void k_final(const float* __restrict__ ceSum,
                        const float* __restrict__ maskSum,
                        float* __restrict__ out) {
    if (threadIdx.x == 0) {
        float s = 0.f;
        for (int b = 0; b < Bn; ++b) s += ceSum[b] / maskSum[b];
        out[0] = s;
    }
}

extern "C" void kernel_launch(void* const* d_in, const int* in_sizes, int n_in,
                              void* d_out, int out_size, void* d_ws, size_t ws_size,
                              hipStream_t stream) {
    const float* x     = (const float*)d_in[0];  // [B,D,H,W] f32
    const int*   label = (const int*)d_in[1];    // [B,H,W]
    const int*   mask  = (const int*)d_in[2];    // [B,1,H,W]
    float* out = (float*)d_out;

    float* ws       = (float*)d_ws;
    float* protoSum = ws;                         // Bn*Cn*Dn = 8192
    float* counts   = protoSum + Bn * Cn * Dn;    // Bn*Cn = 64
    float* maskSum  = counts + Bn * Cn;           // Bn
    float* ceSum    = maskSum + Bn;               // Bn

    size_t zero_bytes = (size_t)(Bn * Cn * Dn + Bn * Cn + Bn + Bn) * sizeof(float);
    hipMemsetAsync(d_ws, 0, zero_bytes, stream);

    k_counts<<<Bn * 16, 256, 0, stream>>>(label, mask, counts, maskSum);
    k_proto <<<Bn * Dn, 256, 0, stream>>>(x, label, protoSum);
    k_main  <<<Bn * 64, 256, 0, stream>>>(x, label, mask, protoSum, counts, ceSum);
    k_final <<<1, 64, 0, stream>>>(ceSum, maskSum, out);
}

// Round 2
// 53.318 us; speedup vs baseline: 1.3222x; 1.3222x over previous
//
#include <hip/hip_runtime.h>

// Problem constants (match reference)
constexpr int Bn = 4, Dn = 128, Hn = 128, Wn = 128, Cn = 16;
constexpr int NPIX = Hn * Wn;  // 16384
constexpr int PS = 4;          // pixel chunks per (b,d) in k_proto

// ---------------------------------------------------------------------------
// K1: per-batch class counts + mask sum via ballot/popc (SALU-cheap).
// grid = Bn * (NPIX/256) = 256 blocks, 256 threads, 1 pixel/thread.
// ---------------------------------------------------------------------------
__global__ void k_counts(const int* __restrict__ label,
                         const int* __restrict__ mask,
                         float* __restrict__ counts,    // [Bn][Cn]
                         float* __restrict__ maskSum) { // [Bn]
    int b = blockIdx.x >> 6;        // 64 blocks per batch
    int p = ((blockIdx.x & 63) << 8) + threadIdx.x;
    int tid = threadIdx.x;
    int wid = tid >> 6, lane = tid & 63;

    int l = label[b * NPIX + p] - 1;
    int m = mask[b * NPIX + p];

    __shared__ int red[4][Cn + 1];
    int cnt[Cn + 1];
#pragma unroll
    for (int c = 0; c < Cn; ++c) {
        unsigned long long bal = __ballot(l == c);
        cnt[c] = (int)__popcll(bal);
    }
    {
        unsigned long long bal = __ballot(m != 0);
        cnt[Cn] = (int)__popcll(bal);
    }
    if (lane == 0) {
#pragma unroll
        for (int c = 0; c <= Cn; ++c) red[wid][c] = cnt[c];
    }
    __syncthreads();
    if (tid < Cn + 1) {
        int s = red[0][tid] + red[1][tid] + red[2][tid] + red[3][tid];
        if (tid < Cn) atomicAdd(&counts[b * Cn + tid], (float)s);
        else          atomicAdd(&maskSum[b], (float)s);
    }
}

// ---------------------------------------------------------------------------
// K2: prototype sums. Block per (b, d, pixel-chunk); each block covers
// NPIX/PS = 4096 pixels for one d, float4 x + int4 label loads, predicated
// per-class accumulation, wave+LDS reduce, 16 atomicAdds per block.
// grid = Bn*Dn*PS = 2048 blocks, 256 threads -> 8 blocks/CU, 32 waves/CU.
// ---------------------------------------------------------------------------
__global__ void k_proto(const float* __restrict__ x,
                        const int* __restrict__ label,
                        float* __restrict__ protoSum) { // [Bn][Cn][Dn]
    int bid = blockIdx.x;
    int chunk = bid & (PS - 1);
    int d = (bid >> 2) & (Dn - 1);
    int b = bid >> 9;               // Dn*PS = 512 blocks per batch
    int tid = threadIdx.x;

    constexpr int CH = NPIX / PS;   // 4096 pixels per block
    const float4* xp = (const float4*)(x + (size_t)(b * Dn + d) * NPIX + chunk * CH);
    const int4*   lp = (const int4*)(label + (size_t)b * NPIX + chunk * CH);

    float acc[Cn];
#pragma unroll
    for (int c = 0; c < Cn; ++c) acc[c] = 0.f;

    for (int i = tid; i < CH / 4; i += 256) {   // 4 iterations
        float4 xv = xp[i];
        int4 lv = lp[i];
        int l0 = lv.x - 1, l1 = lv.y - 1, l2 = lv.z - 1, l3 = lv.w - 1;
#pragma unroll
        for (int c = 0; c < Cn; ++c) {
            acc[c] += ((l0 == c) ? xv.x : 0.f) + ((l1 == c) ? xv.y : 0.f)
                    + ((l2 == c) ? xv.z : 0.f) + ((l3 == c) ? xv.w : 0.f);
        }
    }

#pragma unroll
    for (int c = 0; c < Cn; ++c)
        for (int off = 32; off; off >>= 1) acc[c] += __shfl_down(acc[c], off);

    __shared__ float red[4][Cn];
    int wid = tid >> 6, lane = tid & 63;
    if (lane == 0) {
#pragma unroll
        for (int c = 0; c < Cn; ++c) red[wid][c] = acc[c];
    }
    __syncthreads();
    if (tid < Cn) {
        float s = red[0][tid] + red[1][tid] + red[2][tid] + red[3][tid];
        atomicAdd(&protoSum[((size_t)b * Cn + tid) * Dn + d], s);
    }
}

// ---------------------------------------------------------------------------
// K3: metric + CE. Block = 256 threads covers 64 pixels; wave w handles
// d in [32w, 32w+32). Partials combined via conflict-free LDS [dg][c][pix];
// epilogue (softmax/CE/mask) on wave 0. grid = Bn*256 = 1024 blocks.
// ---------------------------------------------------------------------------
__global__ void k_main(const float* __restrict__ x,
                       const int* __restrict__ label,
                       const int* __restrict__ mask,
                       const float* __restrict__ protoSum,
                       const float* __restrict__ counts,
                       float* __restrict__ ceSum) { // [Bn]
    int b = blockIdx.x >> 8;                 // 256 blocks per batch
    int pbase = (blockIdx.x & 255) << 6;     // 64 pixels per block
    int tid = threadIdx.x;
    int pix = tid & 63, dg = tid >> 6;       // dg in 0..3

    __shared__ float proto[Dn][Cn];          // 8 KB, [d][c]
    for (int i = tid; i < Cn * Dn; i += 256) {
        int c = i >> 7;                      // protoSum [c][d] -> coalesced
        int d = i & (Dn - 1);
        proto[d][c] = protoSum[((size_t)b * Cn + c) * Dn + d] / counts[b * Cn + c];
    }
    __syncthreads();

    float acc[Cn];
#pragma unroll
    for (int c = 0; c < Cn; ++c) acc[c] = 0.f;

    const float* xp = x + (size_t)b * Dn * NPIX + pbase + pix;
#pragma unroll 4
    for (int dd = 0; dd < 32; ++dd) {
        int d = (dg << 5) + dd;
        float xv = xp[(size_t)d * NPIX];
        float4 q0 = *(const float4*)&proto[d][0];
        float4 q1 = *(const float4*)&proto[d][4];
        float4 q2 = *(const float4*)&proto[d][8];
        float4 q3 = *(const float4*)&proto[d][12];
        acc[0]  += fabsf(xv - q0.x);  acc[1]  += fabsf(xv - q0.y);
        acc[2]  += fabsf(xv - q0.z);  acc[3]  += fabsf(xv - q0.w);
        acc[4]  += fabsf(xv - q1.x);  acc[5]  += fabsf(xv - q1.y);
        acc[6]  += fabsf(xv - q1.z);  acc[7]  += fabsf(xv - q1.w);
        acc[8]  += fabsf(xv - q2.x);  acc[9]  += fabsf(xv - q2.y);
        acc[10] += fabsf(xv - q2.z);  acc[11] += fabsf(xv - q2.w);
        acc[12] += fabsf(xv - q3.x);  acc[13] += fabsf(xv - q3.y);
        acc[14] += fabsf(xv - q3.z);  acc[15] += fabsf(xv - q3.w);
    }

    // combine the 4 d-groups' partials: [dg][c][pix] is conflict-free both ways
    __shared__ float part[4][Cn][64];        // 16 KB
#pragma unroll
    for (int c = 0; c < Cn; ++c) part[dg][c][pix] = acc[c];
    __syncthreads();

    if (tid < 64) {
        float a[Cn];
#pragma unroll
        for (int c = 0; c < Cn; ++c)
            a[c] = part[0][c][tid] + part[1][c][tid] + part[2][c][tid] + part[3][c][tid];

        float pd0[Cn];
        float mn = 3.4e38f;
#pragma unroll
        for (int c = 0; c < Cn; ++c) {
            pd0[c] = __expf(-a[c]);
            mn = fminf(mn, pd0[c]);
        }
        float se = 0.f;
#pragma unroll
        for (int c = 0; c < Cn; ++c) se += __expf(pd0[c] - mn);

        int p = pbase + tid;
        int l = label[b * NPIX + p] - 1;
        float pdl = 0.f;
#pragma unroll
        for (int c = 0; c < Cn; ++c) pdl = (l == c) ? (pd0[c] - mn) : pdl;

        float ce = __logf(se) - pdl;
        float m = (float)mask[b * NPIX + p];
        float v = ce * m;

        for (int off = 32; off; off >>= 1) v += __shfl_down(v, off);
        if (tid == 0) atomicAdd(&ceSum[b], v);
    }
}

// ---------------------------------------------------------------------------
// K4: final scalar combine
// ---------------------------------------------------------------------------
__global__ void k_final(const float* __restrict__ ceSum,
                        const float* __restrict__ maskSum,
                        float* __restrict__ out) {
    if (threadIdx.x == 0) {
        float s = 0.f;
        for (int b = 0; b < Bn; ++b) s += ceSum[b] / maskSum[b];
        out[0] = s;
    }
}

extern "C" void kernel_launch(void* const* d_in, const int* in_sizes, int n_in,
                              void* d_out, int out_size, void* d_ws, size_t ws_size,
                              hipStream_t stream) {
    const float* x     = (const float*)d_in[0];  // [B,D,H,W] f32
    const int*   label = (const int*)d_in[1];    // [B,H,W]
    const int*   mask  = (const int*)d_in[2];    // [B,1,H,W]
    float* out = (float*)d_out;

    float* ws       = (float*)d_ws;
    float* protoSum = ws;                         // Bn*Cn*Dn = 8192
    float* counts   = protoSum + Bn * Cn * Dn;    // Bn*Cn = 64
    float* maskSum  = counts + Bn * Cn;           // Bn
    float* ceSum    = maskSum + Bn;               // Bn

    size_t zero_bytes = (size_t)(Bn * Cn * Dn + Bn * Cn + Bn + Bn) * sizeof(float);
    hipMemsetAsync(d_ws, 0, zero_bytes, stream);

    k_counts<<<Bn * 64, 256, 0, stream>>>(label, mask, counts, maskSum);
    k_proto <<<Bn * Dn * PS, 256, 0, stream>>>(x, label, protoSum);
    k_main  <<<Bn * 256, 256, 0, stream>>>(x, label, mask, protoSum, counts, ceSum);
    k_final <<<1, 64, 0, stream>>>(ceSum, maskSum, out);
}

// Round 3
// 41.811 us; speedup vs baseline: 1.6861x; 1.2752x over previous
//
#include <hip/hip_runtime.h>

// Problem constants (match reference)
constexpr int Bn = 4, Dn = 128, Hn = 128, Wn = 128, Cn = 16;
constexpr int NPIX = Hn * Wn;  // 16384
constexpr int PS = 4;          // pixel chunks per (b,d) in k_proto

// ws layout (floats):
//   protoPart [Bn][PS][Cn][Dn]  = 32768
//   countsPart[Bn][PS][Cn]      = 256
//   maskPart  [Bn][PS]          = 16
//   cePart    [Bn][256]         = 1024
// All written with plain stores every call (no zero-init, no atomics).

// ---------------------------------------------------------------------------
// K1: per-(b,d,chunk) prototype partial sums; d==0 blocks also produce
// label counts + mask count for their chunk. Plain stores only.
// grid = Bn*Dn*PS = 2048 blocks, 256 threads.
// ---------------------------------------------------------------------------
__global__ void k_proto(const float* __restrict__ x,
                        const int* __restrict__ label,
                        const int* __restrict__ mask,
                        float* __restrict__ protoPart,   // [Bn][PS][Cn][Dn]
                        float* __restrict__ countsPart,  // [Bn][PS][Cn]
                        float* __restrict__ maskPart) {  // [Bn][PS]
    int bid = blockIdx.x;
    int chunk = bid & (PS - 1);
    int d = (bid >> 2) & (Dn - 1);
    int b = bid >> 9;               // Dn*PS = 512 blocks per batch
    int tid = threadIdx.x;
    int wid = tid >> 6, lane = tid & 63;

    constexpr int CH = NPIX / PS;   // 4096 pixels per block
    const float4* xp = (const float4*)(x + (size_t)(b * Dn + d) * NPIX + chunk * CH);
    const int4*   lp = (const int4*)(label + (size_t)b * NPIX + chunk * CH);

    float acc[Cn];
    int   cnt[Cn];
#pragma unroll
    for (int c = 0; c < Cn; ++c) { acc[c] = 0.f; cnt[c] = 0; }

    for (int i = tid; i < CH / 4; i += 256) {   // 4 iterations
        float4 xv = xp[i];
        int4 lv = lp[i];
        int l0 = lv.x - 1, l1 = lv.y - 1, l2 = lv.z - 1, l3 = lv.w - 1;
#pragma unroll
        for (int c = 0; c < Cn; ++c) {
            acc[c] += ((l0 == c) ? xv.x : 0.f) + ((l1 == c) ? xv.y : 0.f)
                    + ((l2 == c) ? xv.z : 0.f) + ((l3 == c) ? xv.w : 0.f);
            if (d == 0)
                cnt[c] += (l0 == c) + (l1 == c) + (l2 == c) + (l3 == c);
        }
    }

#pragma unroll
    for (int c = 0; c < Cn; ++c)
        for (int off = 32; off; off >>= 1) acc[c] += __shfl_down(acc[c], off);

    __shared__ float red[4][Cn];
    if (lane == 0) {
#pragma unroll
        for (int c = 0; c < Cn; ++c) red[wid][c] = acc[c];
    }
    __syncthreads();
    if (tid < Cn) {
        float s = red[0][tid] + red[1][tid] + red[2][tid] + red[3][tid];
        protoPart[(((size_t)b * PS + chunk) * Cn + tid) * Dn + d] = s;
    }

    if (d == 0) {   // block-uniform branch: counts + mask sum for this chunk
        int msum = 0;
        const int4* mp = (const int4*)(mask + (size_t)b * NPIX + chunk * CH);
        for (int i = tid; i < CH / 4; i += 256) {
            int4 mv = mp[i];
            msum += mv.x + mv.y + mv.z + mv.w;
        }
#pragma unroll
        for (int c = 0; c < Cn; ++c)
            for (int off = 32; off; off >>= 1) cnt[c] += __shfl_down(cnt[c], off);
        for (int off = 32; off; off >>= 1) msum += __shfl_down(msum, off);

        __shared__ int redi[4][Cn + 1];
        if (lane == 0) {
#pragma unroll
            for (int c = 0; c < Cn; ++c) redi[wid][c] = cnt[c];
            redi[wid][Cn] = msum;
        }
        __syncthreads();
        if (tid < Cn) {
            int s = redi[0][tid] + redi[1][tid] + redi[2][tid] + redi[3][tid];
            countsPart[((size_t)b * PS + chunk) * Cn + tid] = (float)s;
        }
        if (tid == Cn) {
            int s = redi[0][Cn] + redi[1][Cn] + redi[2][Cn] + redi[3][Cn];
            maskPart[b * PS + chunk] = (float)s;
        }
    }
}

// ---------------------------------------------------------------------------
// K2: metric + CE. Block = 256 threads covers 64 pixels; wave w handles
// d in [32w, 32w+32). Proto staged in LDS from the 4 chunk-partials.
// Per-block CE partial -> plain store to cePart. grid = Bn*256 = 1024.
// ---------------------------------------------------------------------------
__global__ void k_main(const float* __restrict__ x,
                       const int* __restrict__ label,
                       const int* __restrict__ mask,
                       const float* __restrict__ protoPart,
                       const float* __restrict__ countsPart,
                       float* __restrict__ cePart) { // [Bn][256]
    int b = blockIdx.x >> 8;                 // 256 blocks per batch
    int pbase = (blockIdx.x & 255) << 6;     // 64 pixels per block
    int tid = threadIdx.x;
    int pix = tid & 63, dg = tid >> 6;       // dg in 0..3

    __shared__ float cntInv[Cn];
    if (tid < Cn) {
        float s = 0.f;
#pragma unroll
        for (int ch = 0; ch < PS; ++ch)
            s += countsPart[((size_t)b * PS + ch) * Cn + tid];
        cntInv[tid] = 1.f / s;
    }
    __syncthreads();

    __shared__ float proto[Dn][Cn];          // 8 KB, [d][c]
    for (int i = tid; i < Cn * Dn; i += 256) {
        int c = i >> 7;
        int d = i & (Dn - 1);
        float s = 0.f;
#pragma unroll
        for (int ch = 0; ch < PS; ++ch)
            s += protoPart[(((size_t)b * PS + ch) * Cn + c) * Dn + d];
        proto[d][c] = s * cntInv[c];
    }
    __syncthreads();

    float acc[Cn];
#pragma unroll
    for (int c = 0; c < Cn; ++c) acc[c] = 0.f;

    const float* xp = x + (size_t)b * Dn * NPIX + pbase + pix;
#pragma unroll 4
    for (int dd = 0; dd < 32; ++dd) {
        int d = (dg << 5) + dd;
        float xv = xp[(size_t)d * NPIX];
        float4 q0 = *(const float4*)&proto[d][0];
        float4 q1 = *(const float4*)&proto[d][4];
        float4 q2 = *(const float4*)&proto[d][8];
        float4 q3 = *(const float4*)&proto[d][12];
        acc[0]  += fabsf(xv - q0.x);  acc[1]  += fabsf(xv - q0.y);
        acc[2]  += fabsf(xv - q0.z);  acc[3]  += fabsf(xv - q0.w);
        acc[4]  += fabsf(xv - q1.x);  acc[5]  += fabsf(xv - q1.y);
        acc[6]  += fabsf(xv - q1.z);  acc[7]  += fabsf(xv - q1.w);
        acc[8]  += fabsf(xv - q2.x);  acc[9]  += fabsf(xv - q2.y);
        acc[10] += fabsf(xv - q2.z);  acc[11] += fabsf(xv - q2.w);
        acc[12] += fabsf(xv - q3.x);  acc[13] += fabsf(xv - q3.y);
        acc[14] += fabsf(xv - q3.z);  acc[15] += fabsf(xv - q3.w);
    }

    // combine the 4 d-groups' partials: [dg][c][pix] conflict-free both ways
    __shared__ float part[4][Cn][64];        // 16 KB
#pragma unroll
    for (int c = 0; c < Cn; ++c) part[dg][c][pix] = acc[c];
    __syncthreads();

    if (tid < 64) {
        float a[Cn];
#pragma unroll
        for (int c = 0; c < Cn; ++c)
            a[c] = part[0][c][tid] + part[1][c][tid] + part[2][c][tid] + part[3][c][tid];

        float pd0[Cn];
        float mn = 3.4e38f;
#pragma unroll
        for (int c = 0; c < Cn; ++c) {
            pd0[c] = __expf(-a[c]);
            mn = fminf(mn, pd0[c]);
        }
        float se = 0.f;
#pragma unroll
        for (int c = 0; c < Cn; ++c) se += __expf(pd0[c] - mn);

        int p = pbase + tid;
        int l = label[b * NPIX + p] - 1;
        float pdl = 0.f;
#pragma unroll
        for (int c = 0; c < Cn; ++c) pdl = (l == c) ? (pd0[c] - mn) : pdl;

        float ce = __logf(se) - pdl;
        float m = (float)mask[b * NPIX + p];
        float v = ce * m;

        for (int off = 32; off; off >>= 1) v += __shfl_down(v, off);
        if (tid == 0) cePart[blockIdx.x] = v;   // [b*256 + blk]
    }
}

// ---------------------------------------------------------------------------
// K3: final combine. 1 block, 256 threads; wave w reduces batch w.
// ---------------------------------------------------------------------------
__global__ void k_final(const float* __restrict__ cePart,   // [Bn][256]
                        const float* __restrict__ maskPart, // [Bn][PS]
                        float* __restrict__ out) {
    int tid = threadIdx.x;
    int w = tid >> 6, lane = tid & 63;

    float s = cePart[w * 256 + lane]       + cePart[w * 256 + lane + 64]
            + cePart[w * 256 + lane + 128] + cePart[w * 256 + lane + 192];
    for (int off = 32; off; off >>= 1) s += __shfl_down(s, off);

    __shared__ float r[4];
    if (lane == 0) {
        float ms = maskPart[w * PS + 0] + maskPart[w * PS + 1]
                 + maskPart[w * PS + 2] + maskPart[w * PS + 3];
        r[w] = s / ms;
    }
    __syncthreads();
    if (tid == 0) out[0] = r[0] + r[1] + r[2] + r[3];
}

extern "C" void kernel_launch(void* const* d_in, const int* in_sizes, int n_in,
                              void* d_out, int out_size, void* d_ws, size_t ws_size,
                              hipStream_t stream) {
    const float* x     = (const float*)d_in[0];  // [B,D,H,W] f32
    const int*   label = (const int*)d_in[1];    // [B,H,W]
    const int*   mask  = (const int*)d_in[2];    // [B,1,H,W]
    float* out = (float*)d_out;

    float* ws         = (float*)d_ws;
    float* protoPart  = ws;                               // 32768
    float* countsPart = protoPart + Bn * PS * Cn * Dn;    // 256
    float* maskPart   = countsPart + Bn * PS * Cn;        // 16
    float* cePart     = maskPart + Bn * PS;               // 1024

    k_proto<<<Bn * Dn * PS, 256, 0, stream>>>(x, label, mask,
                                              protoPart, countsPart, maskPart);
    k_main <<<Bn * 256, 256, 0, stream>>>(x, label, mask,
                                          protoPart, countsPart, cePart);
    k_final<<<1, 256, 0, stream>>>(cePart, maskPart, out);
}